// Round 11
// baseline (96.527 us; speedup 1.0000x reference)
//
#include <hip/hip_runtime.h>

// EntityAttention — round 11: associativity restructure. Precompute
// VWt[b][h][o][s] = Wo_h @ V_h^T once per (batch,head); the per-slot kernel
// is then softmax + ONE register-accumulated GEMM over both heads
// (out = sum_h P_h @ VWt_h^T). Removes PV->ctx->outGEMM serial chain.
// NB=8 SL=512 NH=512 EN=16 NE=64 HEADS=2 DH=256. Selection masks all-True.

#define NB 8
#define SL 512
#define NH 512
#define EN 16
#define NE 64
#define HEADS 2
#define DH 256
#define NSLOT (NB * EN)
#define SCALE 0.0625f

typedef __attribute__((ext_vector_type(8))) short short8;
typedef __attribute__((ext_vector_type(4))) short short4v;
typedef __attribute__((ext_vector_type(4))) float f32x4;

#define MFMA16(a, b, c) __builtin_amdgcn_mfma_f32_16x16x32_bf16(a, b, c, 0, 0, 0)

__device__ __forceinline__ short f2b(float f) {
    unsigned u = __builtin_bit_cast(unsigned, f);
    u += 0x7fffu + ((u >> 16) & 1u);
    return (short)(u >> 16);
}
__device__ __forceinline__ float b2f(short s) {
    return __builtin_bit_cast(float, ((unsigned)(unsigned short)s) << 16);
}
// XCD-chunk swizzle: grid = 8*chunk, hw round-robins XCDs -> logical chunks.
__device__ __forceinline__ int swz8(int hw, int chunk) {
    return (hw & 7) * chunk + (hw >> 3);
}

// ---- tiny GEMM helpers (static-index, fully inlined) -----------------------
__device__ __forceinline__ void ldg4(short8 (&d)[4], const short* p, int k, int stride) {
#pragma unroll
    for (int j = 0; j < 4; ++j) d[j] = *(const short8*)(p + (size_t)j * 16 * stride + k);
}
__device__ __forceinline__ void ldg2(short8 (&d)[2], const short* p, int k, int stride) {
#pragma unroll
    for (int j = 0; j < 2; ++j) d[j] = *(const short8*)(p + (size_t)j * 16 * stride + k);
}
__device__ __forceinline__ void ldsw2(short8 (&d)[2], const short* Ph, int k, int kb, int l15) {
    int g = (k + kb) >> 3;
#pragma unroll
    for (int i = 0; i < 2; ++i) {
        int el = i * 16 + l15;
        d[i] = *(const short8*)&Ph[el * SL + ((g ^ (el & 7)) * 8)];
    }
}
__device__ __forceinline__ void mm44(f32x4 (&acc)[4][4], const short8 (&a)[4], const short8 (&bb)[4]) {
#pragma unroll
    for (int i = 0; i < 4; ++i)
#pragma unroll
        for (int j = 0; j < 4; ++j) acc[i][j] = MFMA16(a[i], bb[j], acc[i][j]);
}
__device__ __forceinline__ void mm42(f32x4 (&acc)[4][2], const short8 (&a)[4], const short8 (&bb)[2]) {
#pragma unroll
    for (int i = 0; i < 4; ++i)
#pragma unroll
        for (int j = 0; j < 2; ++j) acc[i][j] = MFMA16(a[i], bb[j], acc[i][j]);
}
__device__ __forceinline__ void mm24(f32x4 (&acc)[2][4], const short8 (&a)[2], const short8 (&bb)[4]) {
#pragma unroll
    for (int i = 0; i < 2; ++i)
#pragma unroll
        for (int j = 0; j < 4; ++j) acc[i][j] = MFMA16(a[i], bb[j], acc[i][j]);
}

// ---- ws byte offsets (no aliasing) -----------------------------------------
#define WS_TOKS 0u
#define WS_K (4u << 20)
#define WS_V (8u << 20)
#define WS_S (20u << 20)
#define WS_WK (22u << 20)
#define WS_WV (WS_WK + (512u << 10))
#define WS_WO (WS_WV + (512u << 10))
#define WS_WQ (WS_WO + (512u << 10))
#define WS_EV (WS_WQ + (512u << 10))
#define WS_Q (WS_EV + (64u << 10))
#define WS_FLAG (WS_Q + (64u << 10))
#define WS_VW (24u << 20) /* 16 x 512KB = 8 MB */

// chunk counts (f32x4 units) for prep
#define CH_TOKS (NB * SL * NH / 4) /* 524288 */
#define CH_W (NH * NH / 4)         /* 65536 */
#define CH_EV (NE * NH / 4)        /* 8192 */
#define CH_TOTAL (CH_TOKS + 4 * CH_W + CH_EV) /* 794624 */

// ---------------------------------------------------------------------------
// prep: all fp32->bf16 conversions + bool-encoding detection (last block).
__global__ void prep_kernel(const float* __restrict__ toks, const float* __restrict__ Wk,
                            const float* __restrict__ Wv, const float* __restrict__ Wo,
                            const float* __restrict__ Wq, const float* __restrict__ ev,
                            const unsigned char* __restrict__ ents,
                            short* __restrict__ toks_bf, short* __restrict__ Wk_bf,
                            short* __restrict__ Wv_bf, short* __restrict__ Wo_bf,
                            short* __restrict__ Wq_bf, short* __restrict__ ev_bf,
                            int* __restrict__ flag) {
    __shared__ int red[256];
    int idx = blockIdx.x * 256 + threadIdx.x;
    if (idx < CH_TOTAL) {
        const float* src;
        short* dst;
        int off = idx;
        if (idx < CH_TOKS) { src = toks; dst = toks_bf; }
        else if (idx < CH_TOKS + CH_W) { src = Wk; dst = Wk_bf; off -= CH_TOKS; }
        else if (idx < CH_TOKS + 2 * CH_W) { src = Wv; dst = Wv_bf; off -= CH_TOKS + CH_W; }
        else if (idx < CH_TOKS + 3 * CH_W) { src = Wo; dst = Wo_bf; off -= CH_TOKS + 2 * CH_W; }
        else if (idx < CH_TOKS + 4 * CH_W) { src = Wq; dst = Wq_bf; off -= CH_TOKS + 3 * CH_W; }
        else { src = ev; dst = ev_bf; off -= CH_TOKS + 4 * CH_W; }
        f32x4 v = ((const f32x4*)src)[off];
        short4v o;
#pragma unroll
        for (int j = 0; j < 4; ++j) o[j] = f2b(v[j]);
        ((short4v*)dst)[off] = o;
    }
    if (blockIdx.x == gridDim.x - 1) {
        int tid = threadIdx.x;
        int cnt = 0;
        for (int j = 0; j < 16; ++j) {
            int off = tid * 16 + j;
            if ((off & 3) != 0 && ents[off] != 0) cnt++;
        }
        red[tid] = cnt;
        __syncthreads();
        for (int s = 128; s > 0; s >>= 1) {
            if (tid < s) red[tid] += red[tid + s];
            __syncthreads();
        }
        if (tid == 0) flag[0] = (red[0] == 0) ? 1 : 0;
    }
}

// ---------------------------------------------------------------------------
// proj: hw<256: K/V tiles (both row-major now); hw>=256: q.
// K/V: 128x128 block tile, 4 waves of 64x64 (4x4 frags), 2-deep pipeline.
__global__ void __launch_bounds__(256, 2)
proj_kernel(const short* __restrict__ toks_bf,
            const short* __restrict__ Wk_bf,
            const short* __restrict__ Wv_bf,
            const short* __restrict__ ev_bf,
            const short* __restrict__ Wq_bf,
            const float* __restrict__ bk, const float* __restrict__ bv,
            const float* __restrict__ bq,
            short* __restrict__ K_bf, short* __restrict__ V_bf,
            short* __restrict__ q_bf) {
    int t = blockIdx.x;
    int tid = threadIdx.x, lane = tid & 63, wid = tid >> 6;
    int l15 = lane & 15;
    int kb = (lane >> 4) * 8;
    int crow = (lane >> 4) * 4;

    if (t < 256) {
        int l = swz8(t, 32); // batch-major: b*32 + kind*16 + mt*4 + nt
        int b = l >> 5, kind = (l >> 4) & 1, mt = (l >> 2) & 3, nt = l & 3;
        int m0 = mt * 128 + (wid >> 1) * 64;
        int n0 = nt * 128 + (wid & 1) * 64;
        const short* A = toks_bf + ((size_t)b * SL + m0 + l15) * NH + kb;
        const short* B = (kind ? Wv_bf : Wk_bf) + (size_t)(n0 + l15) * NH + kb;
        const float* bias = kind ? bv : bk;
        short* dst = kind ? V_bf : K_bf;

        f32x4 acc[4][4];
#pragma unroll
        for (int i = 0; i < 4; ++i)
#pragma unroll
            for (int j = 0; j < 4; ++j) acc[i][j] = (f32x4)0.f;

        short8 a0[4], b0[4], a1[4], b1[4];
        ldg4(a0, A, 0, NH);
        ldg4(b0, B, 0, NH);
#pragma unroll
        for (int p = 0; p < 8; ++p) {
            int k1 = p * 64 + 32;
            ldg4(a1, A, k1, NH);
            ldg4(b1, B, k1, NH);
            mm44(acc, a0, b0);
            if (p < 7) {
                ldg4(a0, A, k1 + 32, NH);
                ldg4(b0, B, k1 + 32, NH);
            }
            mm44(acc, a1, b1);
        }

#pragma unroll
        for (int i = 0; i < 4; ++i) {
#pragma unroll
            for (int j = 0; j < 4; ++j) {
                int col = n0 + j * 16 + l15;
                float bval = bias[col];
                int row0 = m0 + i * 16 + crow;
#pragma unroll
                for (int r = 0; r < 4; ++r)
                    dst[((size_t)b * SL + row0 + r) * NH + col] = f2b(acc[i][j][r] + bval);
            }
        }
    } else {
        // q projection: M=64, N=512 over 4 blocks; wave = 64e x 32cols.
        int tq = t - 256; // 0..3
        int n0 = tq * 128 + wid * 32;
        const short* A = ev_bf + (size_t)l15 * NH + kb;
        const short* B = Wq_bf + (size_t)(n0 + l15) * NH + kb;

        f32x4 acc[4][2];
#pragma unroll
        for (int i = 0; i < 4; ++i)
#pragma unroll
            for (int j = 0; j < 2; ++j) acc[i][j] = (f32x4)0.f;

        for (int k = 0; k < NH; k += 32) {
            short8 a[4], bb[2];
#pragma unroll
            for (int i = 0; i < 4; ++i) a[i] = *(const short8*)(A + (size_t)i * 16 * NH + k);
#pragma unroll
            for (int j = 0; j < 2; ++j) bb[j] = *(const short8*)(B + (size_t)j * 16 * NH + k);
            mm42(acc, a, bb);
        }

#pragma unroll
        for (int i = 0; i < 4; ++i)
#pragma unroll
            for (int j = 0; j < 2; ++j) {
                int col = n0 + j * 16 + l15;
                float bval = bq[col];
#pragma unroll
                for (int r = 0; r < 4; ++r)
                    q_bf[(size_t)(i * 16 + crow + r) * NH + col] = f2b((acc[i][j][r] + bval) * SCALE);
            }
    }
}

// ---------------------------------------------------------------------------
// scores: S_bf[b][h][e][s] = q_scaled[e] . K[b][s] (bf16 out). grid 64.
__global__ void __launch_bounds__(256, 2)
scores_mfma(const short* __restrict__ q_bf,
            const short* __restrict__ K_bf,
            short* __restrict__ S_bf) {
    int l = swz8(blockIdx.x, 8); // b*8 + h*4 + st
    int b = l >> 3, h = (l >> 2) & 1, st = l & 3;
    int tid = threadIdx.x, lane = tid & 63, wid = tid >> 6;
    int l15 = lane & 15;
    int n0 = st * 128 + wid * 32;
    int kb = (lane >> 4) * 8;

    f32x4 acc[4][2];
#pragma unroll
    for (int i = 0; i < 4; ++i)
#pragma unroll
        for (int j = 0; j < 2; ++j) acc[i][j] = (f32x4)0.f;

    const short* Aq = q_bf + (size_t)l15 * NH + h * DH + kb;
    const short* Bk = K_bf + ((size_t)b * SL + n0 + l15) * NH + h * DH + kb;

    short8 a0[4], a1[4];
    short8 b0[2], b1[2];
    ldg4(a0, Aq, 0, NH);
    ldg2(b0, Bk, 0, NH);
#pragma unroll
    for (int p = 0; p < 4; ++p) {
        int k1 = p * 64 + 32;
        ldg4(a1, Aq, k1, NH);
        ldg2(b1, Bk, k1, NH);
        mm42(acc, a0, b0);
        if (p < 3) {
            ldg4(a0, Aq, k1 + 32, NH);
            ldg2(b0, Bk, k1 + 32, NH);
        }
        mm42(acc, a1, b1);
    }

    int crow = (lane >> 4) * 4;
#pragma unroll
    for (int i = 0; i < 4; ++i)
#pragma unroll
        for (int j = 0; j < 2; ++j) {
            int col = n0 + j * 16 + l15;
#pragma unroll
            for (int r = 0; r < 4; ++r) {
                int row = i * 16 + crow + r;
                S_bf[(((size_t)(b * HEADS + h)) * NE + row) * SL + col] = f2b(acc[i][j][r]);
            }
        }
}

// ---------------------------------------------------------------------------
// vwt: VWt[b][h][o][s] = sum_d Wo[o][h*DH+d] * V[b][s][h*DH+d], bf16.
// Per (b,h): 512x512 output = 16 x (128x128 tiles); grid 256, K=256.
__global__ void __launch_bounds__(256, 2)
vwt_kernel(const short* __restrict__ V_bf,
           const short* __restrict__ Wo_bf,
           short* __restrict__ VWt) {
    int l = swz8(blockIdx.x, 32); // bh*16 + mt*4 + nt
    int bh = l >> 4, mt = (l >> 2) & 3, nt = l & 3;
    int b = bh >> 1, h = bh & 1;
    int tid = threadIdx.x, lane = tid & 63, wid = tid >> 6;
    int l15 = lane & 15;
    int kb = (lane >> 4) * 8;
    int crow = (lane >> 4) * 4;
    int m0 = mt * 128 + (wid >> 1) * 64; // o rows
    int n0 = nt * 128 + (wid & 1) * 64;  // s rows

    const short* A = Wo_bf + (size_t)(m0 + l15) * NH + h * DH + kb;
    const short* B = V_bf + ((size_t)b * SL + n0 + l15) * NH + h * DH + kb;

    f32x4 acc[4][4];
#pragma unroll
    for (int i = 0; i < 4; ++i)
#pragma unroll
        for (int j = 0; j < 4; ++j) acc[i][j] = (f32x4)0.f;

    short8 a0[4], b0[4], a1[4], b1[4];
    ldg4(a0, A, 0, NH);
    ldg4(b0, B, 0, NH);
#pragma unroll
    for (int p = 0; p < 4; ++p) {
        int k1 = p * 64 + 32;
        ldg4(a1, A, k1, NH);
        ldg4(b1, B, k1, NH);
        mm44(acc, a0, b0);
        if (p < 3) {
            ldg4(a0, A, k1 + 32, NH);
            ldg4(b0, B, k1 + 32, NH);
        }
        mm44(acc, a1, b1);
    }

    short* dst = VWt + (size_t)bh * NH * SL;
#pragma unroll
    for (int i = 0; i < 4; ++i)
#pragma unroll
        for (int j = 0; j < 4; ++j) {
            int col = n0 + j * 16 + l15;
            int row0 = m0 + i * 16 + crow;
#pragma unroll
            for (int r = 0; r < 4; ++r)
                dst[(size_t)(row0 + r) * SL + col] = f2b(acc[i][j][r]);
        }
}

// ---------------------------------------------------------------------------
// attn2: softmax + single accumulated GEMM over both heads.
// Block = (slot n, e-half eh), 512 thr (8 waves). LDS: P[32][512] (32 KB),
// reused per head. out[e][o] = sum_h sum_s P_h[e][s] * VWt[b][h][o][s] + bo.
__global__ void __launch_bounds__(512, 2)
attn2(const short* __restrict__ S_bf,
      const short* __restrict__ VWt,
      const void* __restrict__ ents,
      const int* __restrict__ flag,
      const float* __restrict__ bo,
      float* __restrict__ out) {
    __shared__ short Pld[32 * SL]; // 32 KB
    int l = swz8(blockIdx.x, 32); // b*32 + ent*2 + eh
    int b = l >> 5;
    int ent = (l >> 1) & 15, eh = l & 1;
    int n = b * EN + ent;
    int tid = threadIdx.x, lane = tid & 63, wid = tid >> 6;
    int l15 = lane & 15;
    int kb = (lane >> 4) * 8;
    int crow = (lane >> 4) * 4;

    // key-padding mask bits for s = lane*8 + j
    unsigned att8 = 0;
    {
        size_t mbase = ((size_t)b * EN + ent) * SL + lane * 8;
        if (flag[0]) {
            const int* p = (const int*)ents;
#pragma unroll
            for (int j = 0; j < 8; ++j)
                if (p[mbase + j]) att8 |= 1u << j;
        } else {
            const unsigned char* p = (const unsigned char*)ents;
#pragma unroll
            for (int j = 0; j < 8; ++j)
                if (p[mbase + j]) att8 |= 1u << j;
        }
    }

    f32x4 oacc[2][4];
#pragma unroll
    for (int i = 0; i < 2; ++i)
#pragma unroll
        for (int j = 0; j < 4; ++j) oacc[i][j] = (f32x4)0.f;

    for (int h = 0; h < HEADS; ++h) {
        // B base for this head: VWt[b][h][o = wid*64 + ...][s]
        const short* Bw = VWt + (size_t)(b * HEADS + h) * NH * SL +
                          (size_t)(wid * 64 + l15) * SL + kb;
        short8 bwA[4], bwB[4];
        ldg4(bwA, Bw, 0, SL); // prefetch iter-0 under softmax
        __builtin_amdgcn_sched_barrier(0);

        // ---- softmax: wave w owns rows el = w*4 .. w*4+3 ----
        {
            const short* Sbase = S_bf +
                (((size_t)(b * HEADS + h)) * NE + eh * 32 + wid * 4) * SL + lane * 8;
            short8 sr[4];
#pragma unroll
            for (int it = 0; it < 4; ++it) sr[it] = *(const short8*)(Sbase + (size_t)it * SL);

            float pall[4][8];
            float sums[4];
#pragma unroll
            for (int it = 0; it < 4; ++it) {
                float s = 0.f;
#pragma unroll
                for (int j = 0; j < 8; ++j) {
                    float v = (att8 >> j & 1) ? b2f(sr[it][j]) : -1e9f;
                    float e = __expf(v);
                    pall[it][j] = e;
                    s += e;
                }
                sums[it] = s;
            }
#pragma unroll
            for (int off = 32; off; off >>= 1)
#pragma unroll
                for (int it = 0; it < 4; ++it) sums[it] += __shfl_xor(sums[it], off);
#pragma unroll
            for (int it = 0; it < 4; ++it) {
                float iv = 1.f / sums[it];
                short8 pv;
#pragma unroll
                for (int j = 0; j < 8; ++j) pv[j] = f2b(pall[it][j] * iv);
                int el = wid * 4 + it;
                *(short8*)&Pld[el * SL + ((lane ^ (el & 7)) * 8)] = pv;
            }
        }
        __syncthreads();

        // ---- GEMM: oacc += P[32x512] @ VWt_h[o][s]^T, 2-deep pipelined ----
        {
            short8 paA[2], paB[2];
            ldsw2(paA, Pld, 0, kb, l15);
#pragma unroll
            for (int p = 0; p < 8; ++p) {
                int k1 = p * 64 + 32;
                ldg4(bwB, Bw, k1, SL);
                ldsw2(paB, Pld, k1, kb, l15);
                mm24(oacc, paA, bwA);
                if (p < 7) {
                    ldg4(bwA, Bw, k1 + 32, SL);
                    ldsw2(paA, Pld, k1 + 32, kb, l15);
                }
                mm24(oacc, paB, bwB);
            }
        }
        if (h == 0) __syncthreads(); // Pld reused by next head's softmax
    }

    // ---- epilogue: out rows ----
    int n0 = wid * 64;
    size_t rbase = (size_t)n * NE + eh * 32;
#pragma unroll
    for (int i = 0; i < 2; ++i)
#pragma unroll
        for (int j = 0; j < 4; ++j) {
            int col = n0 + j * 16 + l15;
            float bval = bo[col];
#pragma unroll
            for (int r = 0; r < 4; ++r) {
                size_t row = rbase + i * 16 + crow + r;
                out[row * NH + col] = oacc[i][j][r] + bval;
            }
        }
}

// ---------------------------------------------------------------------------
extern "C" void kernel_launch(void* const* d_in, const int* in_sizes, int n_in,
                              void* d_out, int out_size, void* d_ws, size_t ws_size,
                              hipStream_t stream) {
    const float* toks = (const float*)d_in[0];
    const void* ents = d_in[1];
    const float* evs = (const float*)d_in[2];
    const float* Wq = (const float*)d_in[6];
    const float* Wk = (const float*)d_in[7];
    const float* Wv = (const float*)d_in[8];
    const float* bq = (const float*)d_in[9];
    const float* bk = (const float*)d_in[10];
    const float* bv = (const float*)d_in[11];
    const float* Wo = (const float*)d_in[12];
    const float* bo = (const float*)d_in[13];

    char* ws = (char*)d_ws;
    short* toks_bf = (short*)(ws + WS_TOKS);
    short* K_bf = (short*)(ws + WS_K);
    short* V_bf = (short*)(ws + WS_V);
    short* S_bf = (short*)(ws + WS_S);
    short* Wk_bf = (short*)(ws + WS_WK);
    short* Wv_bf = (short*)(ws + WS_WV);
    short* Wo_bf = (short*)(ws + WS_WO);
    short* Wq_bf = (short*)(ws + WS_WQ);
    short* ev_bf = (short*)(ws + WS_EV);
    short* q_bf = (short*)(ws + WS_Q);
    int* flag = (int*)(ws + WS_FLAG);
    short* VWt = (short*)(ws + WS_VW);

    prep_kernel<<<CH_TOTAL / 256 + 1, 256, 0, stream>>>(
        toks, Wk, Wv, Wo, Wq, evs, (const unsigned char*)ents,
        toks_bf, Wk_bf, Wv_bf, Wo_bf, Wq_bf, ev_bf, flag);
    proj_kernel<<<260, 256, 0, stream>>>(toks_bf, Wk_bf, Wv_bf, ev_bf, Wq_bf,
                                         bk, bv, bq, K_bf, V_bf, q_bf);
    scores_mfma<<<64, 256, 0, stream>>>(q_bf, K_bf, S_bf);
    vwt_kernel<<<256, 256, 0, stream>>>(V_bf, Wo_bf, VWt);
    attn2<<<256, 512, 0, stream>>>(S_bf, VWt, ents, flag, bo, (float*)d_out);
}